// Round 1
// 153.969 us; speedup vs baseline: 1.0452x; 1.0452x over previous
//
#include <hip/hip_runtime.h>
#include <cfloat>
#include <math.h>

#define BATCH 8
#define CH 256
#define CI 128
#define NPIX 3136   // 56*56
#define NCHUNK 98   // 3136/32
#define NB 4096     // buckets for the scatter sort
#define BN_EPS 1e-5f

typedef __attribute__((ext_vector_type(8))) short bf16x8;   // 8 bf16 in 4 VGPRs
typedef __attribute__((ext_vector_type(4))) float f32x4;

__device__ __forceinline__ float bf2f(unsigned short u) {
    union { unsigned int i; float f; } x; x.i = ((unsigned int)u) << 16; return x.f;
}
__device__ __forceinline__ unsigned short f2bf(float f) {
    union { float f; unsigned int i; } x; x.f = f;
    unsigned int u = x.i;
    return (unsigned short)((u + 0x7FFFu + ((u >> 16) & 1u)) >> 16);  // RNE
}

// ---------------------------------------------------------------------------
// K1: block 0: fold wf into theta/phi weights (+biases).
// blocks 1-8:  swizzle g_w^T into bf16 B-fragments  (K=256, N=128)
// blocks 9-16: swizzle wz_w^T into bf16 B-fragments (K=128, N=256)
// B-frag layout per MFMA 16x16x32: lane l, j: B[k=(l>>4)*8+j][n=l&15]
// ---------------------------------------------------------------------------
__global__ __launch_bounds__(256) void k_fold(
    const float* __restrict__ wf_w,
    const float* __restrict__ theta_w, const float* __restrict__ theta_b,
    const float* __restrict__ phi_w,   const float* __restrict__ phi_b,
    const float* __restrict__ g_w,     const float* __restrict__ wz_w,
    float* __restrict__ ta_w, float* __restrict__ pb_w, float* __restrict__ biases,
    unsigned short* __restrict__ Bfrag_g, unsigned short* __restrict__ Bfrag_w)
{
    const int bk = blockIdx.x, tid = threadIdx.x;
    if (bk == 0) {
        float ta = 0.f, pb = 0.f;
        for (int c = 0; c < CI; ++c) {
            ta += wf_w[c]      * theta_w[c * CH + tid];
            pb += wf_w[CI + c] * phi_w[c * CH + tid];
        }
        ta_w[tid] = ta;
        pb_w[tid] = pb;
        if (tid == 0) {
            float tb = 0.f, pbb = 0.f;
            for (int c = 0; c < CI; ++c) {
                tb  += wf_w[c]      * theta_b[c];
                pbb += wf_w[CI + c] * phi_b[c];
            }
            biases[0] = tb;
            biases[1] = pbb;
        }
    } else if (bk <= 8) {
        const int base_pair = (bk - 1) * 8;
        for (int e = tid; e < 4096; e += 256) {
            int pp = e >> 9, lane = (e >> 3) & 63, j = e & 7;
            int pair = base_pair + pp;
            int ks = pair >> 3, nt = pair & 7;
            int k = ks * 32 + (lane >> 4) * 8 + j;
            int n = nt * 16 + (lane & 15);
            Bfrag_g[(size_t)pair * 512 + lane * 8 + j] = f2bf(g_w[n * CH + k]);
        }
    } else {
        const int base_pair = (bk - 9) * 8;
        for (int e = tid; e < 4096; e += 256) {
            int pp = e >> 9, lane = (e >> 3) & 63, j = e & 7;
            int pair = base_pair + pp;
            int ks = pair >> 4, nt = pair & 15;
            int k = ks * 32 + (lane >> 4) * 8 + j;
            int n = nt * 16 + (lane & 15);
            Bfrag_w[(size_t)pair * 512 + lane * 8 + j] = f2bf(wz_w[n * CI + k]);
        }
    }
}

// ---------------------------------------------------------------------------
// K2 (fused conv+gemm): x tile -> LDS fp32 -> fused {a/bsc dots + bf16
// transpose} (single read of xs) -> MFMA with g_w B-frags -> gxg in PIXEL
// order (coalesced). grid (98, B), block 256. gout aliases dead fp32 tile.
// sync3 removed: nothing reads xs after sync2 (gout aliases xs; MFMA reads
// xsb; reduction reads ra/rp — all distinct arrays).
// ---------------------------------------------------------------------------
__global__ __launch_bounds__(256) void k_gemm(
    const float* __restrict__ x,
    const unsigned short* __restrict__ Bfrag_g,
    const float* __restrict__ g_b,
    const float* __restrict__ ta_w, const float* __restrict__ pb_w,
    const float* __restrict__ biases,
    unsigned short* __restrict__ gxg,
    float* __restrict__ a_out, float* __restrict__ bsc_out)
{
    __shared__ float xs[CH][36];              // 36.9 KB (float4-aligned rows)
    __shared__ unsigned short xsb[32 * 264];  // 16.5 KB bf16 transposed tile
    __shared__ float ra[8][32], rp[8][32];    // 2 KB
    unsigned short* gout = (unsigned short*)&xs[0][0];  // reuse dead xs (8.5 KB need)

    const int b  = blockIdx.y;
    const int n0 = blockIdx.x * 32;
    const int tid = threadIdx.x;

    for (int t = tid; t < CH * 8; t += 256) {
        int c = t >> 3, n4 = t & 7;
        const float4* src = (const float4*)(x + ((size_t)b * CH + c) * NPIX + n0);
        *((float4*)&xs[c][n4 * 4]) = src[n4];
    }
    __syncthreads();

    const int p = tid & 31;        // pixel
    const int g = tid >> 5;        // channel group of 32

    // fused: a/bsc partial dots (fp32) + bf16 transpose, one pass over xs
    {
        const int cbase = g * 32;
        float aa = 0.f, pp = 0.f;
        unsigned int* dst = (unsigned int*)&xsb[p * 264 + cbase];
#pragma unroll
        for (int q = 0; q < 16; ++q) {
            int c0 = cbase + 2 * q;
            float lo = xs[c0][p];
            float hi = xs[c0 + 1][p];
            aa += ta_w[c0] * lo + ta_w[c0 + 1] * hi;
            pp += pb_w[c0] * lo + pb_w[c0 + 1] * hi;
            dst[q] = (unsigned int)f2bf(lo) | ((unsigned int)f2bf(hi) << 16);
        }
        ra[g][p] = aa; rp[g][p] = pp;
    }
    __syncthreads();

    if (tid < 32) {
        float sa = 0.f, sp = 0.f;
#pragma unroll
        for (int gg = 0; gg < 8; ++gg) { sa += ra[gg][tid]; sp += rp[gg][tid]; }
        a_out[b * NPIX + n0 + tid]   = sa + biases[0];
        bsc_out[b * NPIX + n0 + tid] = sp + biases[1];
    }

    // MFMA: D[px(32) x o(128)] = xsb(32x256) * g_wT(256x128)
    const int w = tid >> 6, l = tid & 63, lm = l & 15, lq = l >> 4;
    f32x4 acc[2][2];
#pragma unroll
    for (int mi = 0; mi < 2; ++mi)
#pragma unroll
        for (int ni = 0; ni < 2; ++ni) acc[mi][ni] = (f32x4){0.f, 0.f, 0.f, 0.f};

#pragma unroll
    for (int ks = 0; ks < 8; ++ks) {
        bf16x8 a0 = *(const bf16x8*)&xsb[lm * 264 + ks * 32 + lq * 8];
        bf16x8 a1 = *(const bf16x8*)&xsb[(16 + lm) * 264 + ks * 32 + lq * 8];
        bf16x8 b0 = *(const bf16x8*)(Bfrag_g + ((size_t)(ks * 8 + w * 2) * 64 + l) * 8);
        bf16x8 b1 = *(const bf16x8*)(Bfrag_g + ((size_t)(ks * 8 + w * 2 + 1) * 64 + l) * 8);
        acc[0][0] = __builtin_amdgcn_mfma_f32_16x16x32_bf16(a0, b0, acc[0][0], 0, 0, 0);
        acc[0][1] = __builtin_amdgcn_mfma_f32_16x16x32_bf16(a0, b1, acc[0][1], 0, 0, 0);
        acc[1][0] = __builtin_amdgcn_mfma_f32_16x16x32_bf16(a1, b0, acc[1][0], 0, 0, 0);
        acc[1][1] = __builtin_amdgcn_mfma_f32_16x16x32_bf16(a1, b1, acc[1][1], 0, 0, 0);
    }

#pragma unroll
    for (int mi = 0; mi < 2; ++mi)
#pragma unroll
        for (int ni = 0; ni < 2; ++ni) {
            int o = w * 32 + ni * 16 + lm;
            float gb = g_b[o];
#pragma unroll
            for (int r = 0; r < 4; ++r) {
                int m = mi * 16 + lq * 4 + r;
                gout[m * 136 + o] = f2bf(acc[mi][ni][r] + gb);
            }
        }
    __syncthreads();

    {
        const int n = tid >> 3, ch = tid & 7;
        const uint4* s = (const uint4*)&gout[n * 136 + ch * 16];
        uint4* d = (uint4*)(gxg + ((size_t)(b * NPIX + n0 + n)) * CI + ch * 16);
        d[0] = s[0]; d[1] = s[1];
    }
}

// ---------------------------------------------------------------------------
// K3: per-batch bucket scatter, wave-parallel version.
// Values/buckets held in registers (each thread scatters exactly the indices
// it loaded); min/max via __shfl_xor wave reduce; 4096-bucket exclusive scan
// via per-thread sum-of-4 + wave shfl scan + 16-wave-total scan.
// ~6 barriers instead of ~31. grid (B), block 1024.
// ---------------------------------------------------------------------------
__global__ __launch_bounds__(1024) void k_bucketsort(
    const float* __restrict__ bsc,
    float* __restrict__ s_sorted, int* __restrict__ idx_sorted,
    int* __restrict__ bstart, float* __restrict__ params)
{
    __shared__ int hist[NB];
    __shared__ int cnt[NB];
    __shared__ float wmin[16], wmax[16];
    __shared__ int wtot[16], woff[16];
    __shared__ float sh_min, sh_scale;

    const int b = blockIdx.x, tid = threadIdx.x;
    const int lane = tid & 63, wid = tid >> 6;

    // zero histograms (NB = 4*1024 exactly)
#pragma unroll
    for (int k = 0; k < 4; ++k) { hist[tid + k * 1024] = 0; cnt[tid + k * 1024] = 0; }

    // load values into registers + local min/max
    float v[4];
    float lmin = FLT_MAX, lmax = -FLT_MAX;
#pragma unroll
    for (int k = 0; k < 4; ++k) {
        int i = tid + k * 1024;
        if (i < NPIX) {
            float t = bsc[b * NPIX + i];
            v[k] = t;
            lmin = fminf(lmin, t);
            lmax = fmaxf(lmax, t);
        }
    }
    // wave reduce min/max (no barriers)
#pragma unroll
    for (int m = 32; m >= 1; m >>= 1) {
        lmin = fminf(lmin, __shfl_xor(lmin, m));
        lmax = fmaxf(lmax, __shfl_xor(lmax, m));
    }
    if (lane == 0) { wmin[wid] = lmin; wmax[wid] = lmax; }
    __syncthreads();                       // covers hist/cnt zero + wmin/wmax

    if (tid < 16) {
        float a = wmin[tid], c = wmax[tid];
#pragma unroll
        for (int m = 8; m >= 1; m >>= 1) {
            a = fminf(a, __shfl_xor(a, m));
            c = fmaxf(c, __shfl_xor(c, m));
        }
        if (tid == 0) {
            float range = c - a;
            float scale = (range > 0.f) ? (float)NB / range : 0.f;
            sh_min = a; sh_scale = scale;
            params[b * 2] = a; params[b * 2 + 1] = scale;
        }
    }
    __syncthreads();

    const float bmin = sh_min, scale = sh_scale;
    int q[4];
#pragma unroll
    for (int k = 0; k < 4; ++k) {
        int i = tid + k * 1024;
        if (i < NPIX) {
            int qq = (int)((v[k] - bmin) * scale);
            qq = (qq < 0) ? 0 : ((qq > NB - 1) ? NB - 1 : qq);
            q[k] = qq;
            atomicAdd(&hist[qq], 1);
        }
    }
    __syncthreads();

    // exclusive scan of hist: per-thread 4 + wave shfl scan + wave offsets
    const int base4 = tid * 4;
    int h0 = hist[base4], h1 = hist[base4 + 1], h2 = hist[base4 + 2], h3 = hist[base4 + 3];
    int s = h0 + h1 + h2 + h3;
    int incl = s;
#pragma unroll
    for (int off = 1; off < 64; off <<= 1) {
        int t = __shfl_up(incl, off);
        if (lane >= off) incl += t;
    }
    if (lane == 63) wtot[wid] = incl;
    __syncthreads();
    if (tid < 16) {
        int t = wtot[tid];
        int wi = t;
#pragma unroll
        for (int off = 1; off < 16; off <<= 1) {
            int u = __shfl_up(wi, off);
            if (tid >= off) wi += u;
        }
        woff[tid] = wi - t;                // exclusive wave offset
    }
    __syncthreads();
    int excl = woff[wid] + (incl - s);
    hist[base4]     = excl;
    hist[base4 + 1] = excl + h0;
    hist[base4 + 2] = excl + h0 + h1;
    hist[base4 + 3] = excl + h0 + h1 + h2;
    __syncthreads();

#pragma unroll
    for (int k = 0; k < 4; ++k) {
        int i = tid + k * 1024;
        bstart[b * (NB + 1) + i] = hist[i];
    }
    if (tid == 0) bstart[b * (NB + 1) + NB] = NPIX;

#pragma unroll
    for (int k = 0; k < 4; ++k) {
        int i = tid + k * 1024;
        if (i < NPIX) {
            int pos = hist[q[k]] + atomicAdd(&cnt[q[k]], 1);
            s_sorted[b * NPIX + pos]   = v[k];
            idx_sorted[b * NPIX + pos] = i;
        }
    }
}

// ---------------------------------------------------------------------------
// K4: per-chunk sums, single gather via idx_sorted (staged in LDS).
// grid (NCHUNK, B), block 128.
// ---------------------------------------------------------------------------
__global__ __launch_bounds__(128) void k_csum(
    const unsigned short* __restrict__ gxg,
    const float* __restrict__ s_sorted, const int* __restrict__ idx_sorted,
    float* __restrict__ CS1, float* __restrict__ CS2)
{
    __shared__ int   sidx[32];
    __shared__ float sval[32];
    const int b = blockIdx.y, c = blockIdx.x, o = threadIdx.x;
    const int base = b * NPIX + c * 32;
    if (o < 32) {
        sidx[o] = idx_sorted[base + o];
        sval[o] = s_sorted[base + o];
    }
    __syncthreads();

    float a1 = 0.f, a2 = 0.f;
#pragma unroll 8
    for (int rr = 0; rr < 32; ++rr) {
        float v = bf2f(gxg[((size_t)(b * NPIX + sidx[rr])) * CI + o]);
        a1 += v;
        a2 += sval[rr] * v;
    }
    CS1[(b * 100 + c) * CI + o] = a1;
    CS2[(b * 100 + c) * CI + o] = a2;
}

// ---------------------------------------------------------------------------
// K5: suffix scan over 98 chunks, two-level parallel version.
// 1024 threads = 8 segments x 128 channels; per-segment local suffix scan
// (~13 serial steps instead of 98), segment totals combined in-register.
// grid (B, 2): y=0 -> CS1, y=1 -> CS2. Zeroes rows 98/99.
// ---------------------------------------------------------------------------
__global__ __launch_bounds__(1024) void k_suffix(
    float* __restrict__ CS1, float* __restrict__ CS2)
{
    __shared__ float buf[NCHUNK * CI];   // 49 KB
    __shared__ float tot[8][CI];         // 4 KB
    const int b = blockIdx.x, tid = threadIdx.x;
    float* __restrict__ CS = blockIdx.y ? CS2 : CS1;

    for (int i = tid; i < NCHUNK * CI; i += 1024) buf[i] = CS[b * 100 * CI + i];
    __syncthreads();

    const int seg = tid >> 7, o = tid & 127;
    const int c0 = seg * 13;
    const int c1 = (seg == 7) ? NCHUNK : c0 + 13;   // 13*7 + 7 = 98
    {
        float acc = 0.f;
        for (int c = c1 - 1; c >= c0; --c) {
            acc += buf[c * CI + o];
            buf[c * CI + o] = acc;
        }
        tot[seg][o] = acc;
    }
    __syncthreads();
    {
        float off = 0.f;
#pragma unroll
        for (int s2 = 7; s2 >= 1; --s2) if (s2 > seg) off += tot[s2][o];
        if (off != 0.f || seg < 7) {
            for (int c = c0; c < c1; ++c) buf[c * CI + o] += off;
        }
    }
    __syncthreads();
    for (int i = tid; i < NCHUNK * CI; i += 1024) CS[b * 100 * CI + i] = buf[i];
    if (tid < CI) {
        CS[(b * 100 + 98) * CI + tid] = 0.f;
        CS[(b * 100 + 99) * CI + tid] = 0.f;
    }
}

// ---------------------------------------------------------------------------
// K6 (fused): bucket lookup -> chunk-rounded rank -> y row from L2-resident
// CS tables -> MFMA wz-GEMM -> direct BN+residual epilogue from the MFMA
// C-fragments (4 consecutive pixels per lane = one float4) — no Df LDS
// staging, no final barrier, LDS drops 42 KB -> ~9 KB. grid (98, B), blk 256.
// ---------------------------------------------------------------------------
__global__ __launch_bounds__(256) void k_final(
    const float* __restrict__ x,
    const float* __restrict__ a_arr, const float* __restrict__ wf_b,
    const float* __restrict__ CS1, const float* __restrict__ CS2,
    const int* __restrict__ bstart, const float* __restrict__ params,
    const unsigned short* __restrict__ Bfrag_w,
    const float* __restrict__ wz_b,
    const float* __restrict__ bn_g, const float* __restrict__ bn_b,
    const float* __restrict__ bn_m, const float* __restrict__ bn_v,
    float* __restrict__ out)
{
    __shared__ unsigned short ys[32 * 136];  // bf16 y tile, pad 136
    __shared__ int   rs[32];
    __shared__ float ts[32];

    const int b = blockIdx.y;
    const int n0 = blockIdx.x * 32;
    const int tid = threadIdx.x;

    if (tid < 32) {
        float t = a_arr[b * NPIX + n0 + tid] + wf_b[0];
        float bmin = params[b * 2], scale = params[b * 2 + 1];
        float fq = (-t - bmin) * scale;
        int kb = (int)(fq + 0.5f);
        kb = (kb < 0) ? 0 : ((kb > NB) ? NB : kb);
        int r = bstart[b * (NB + 1) + kb];
        int cstar = (r + 16) >> 5;           // nearest chunk boundary, 0..98
        cstar = (cstar > 98) ? 98 : cstar;
        rs[tid] = cstar;
        ts[tid] = t;
    }
    __syncthreads();

    const int o = tid & 127;
    const int h = tid >> 7;
    const float invN = 1.0f / (float)NPIX;

#pragma unroll 4
    for (int i = 0; i < 16; ++i) {
        int n = h * 16 + i;
        int cb = (b * 100 + rs[n]) * CI + o;
        float S1 = CS1[cb], S2 = CS2[cb];
        ys[n * 136 + o] = f2bf((ts[n] * S1 + S2) * invN);
    }
    __syncthreads();

    const int w = tid >> 6, l = tid & 63, lm = l & 15, lq = l >> 4;

    // hoist BN params per output channel (independent of MFMA; overlaps)
    float invv[4], biasv[4];
#pragma unroll
    for (int ni = 0; ni < 4; ++ni) {
        int cc = w * 64 + ni * 16 + lm;
        float iv = bn_g[cc] * rsqrtf(bn_v[cc] + BN_EPS);
        invv[ni] = iv;
        biasv[ni] = (wz_b[cc] - bn_m[cc]) * iv + bn_b[cc];
    }

    // MFMA: D[px(32) x cc(256)] = ys(32x128) * wz_wT(128x256)
    f32x4 acc[2][4];
#pragma unroll
    for (int mi = 0; mi < 2; ++mi)
#pragma unroll
        for (int ni = 0; ni < 4; ++ni) acc[mi][ni] = (f32x4){0.f, 0.f, 0.f, 0.f};

#pragma unroll
    for (int ks = 0; ks < 4; ++ks) {
        bf16x8 a0 = *(const bf16x8*)&ys[lm * 136 + ks * 32 + lq * 8];
        bf16x8 a1 = *(const bf16x8*)&ys[(16 + lm) * 136 + ks * 32 + lq * 8];
#pragma unroll
        for (int ni = 0; ni < 4; ++ni) {
            bf16x8 bb = *(const bf16x8*)(Bfrag_w + ((size_t)(ks * 16 + w * 4 + ni) * 64 + l) * 8);
            acc[0][ni] = __builtin_amdgcn_mfma_f32_16x16x32_bf16(a0, bb, acc[0][ni], 0, 0, 0);
            acc[1][ni] = __builtin_amdgcn_mfma_f32_16x16x32_bf16(a1, bb, acc[1][ni], 0, 0, 0);
        }
    }

    // direct epilogue: lane fragment = 4 consecutive pixels of one channel
#pragma unroll
    for (int mi = 0; mi < 2; ++mi)
#pragma unroll
        for (int ni = 0; ni < 4; ++ni) {
            int cc = w * 64 + ni * 16 + lm;
            int m  = mi * 16 + lq * 4;
            size_t base = ((size_t)b * CH + cc) * NPIX + n0 + m;
            const float4 xv = *(const float4*)(x + base);
            float4 ov;
            ov.x = acc[mi][ni][0] * invv[ni] + biasv[ni] + xv.x;
            ov.y = acc[mi][ni][1] * invv[ni] + biasv[ni] + xv.y;
            ov.z = acc[mi][ni][2] * invv[ni] + biasv[ni] + xv.z;
            ov.w = acc[mi][ni][3] * invv[ni] + biasv[ni] + xv.w;
            *(float4*)(out + base) = ov;
        }
}

// ---------------------------------------------------------------------------
extern "C" void kernel_launch(void* const* d_in, const int* in_sizes, int n_in,
                              void* d_out, int out_size, void* d_ws, size_t ws_size,
                              hipStream_t stream)
{
    const float* x       = (const float*)d_in[0];
    const float* g_w     = (const float*)d_in[1];
    const float* g_b     = (const float*)d_in[2];
    const float* theta_w = (const float*)d_in[3];
    const float* theta_b = (const float*)d_in[4];
    const float* phi_w   = (const float*)d_in[5];
    const float* phi_b   = (const float*)d_in[6];
    const float* wf_w    = (const float*)d_in[7];
    const float* wf_b    = (const float*)d_in[8];
    const float* wz_w    = (const float*)d_in[9];
    const float* wz_b    = (const float*)d_in[10];
    const float* bn_g    = (const float*)d_in[11];
    const float* bn_b    = (const float*)d_in[12];
    const float* bn_m    = (const float*)d_in[13];
    const float* bn_v    = (const float*)d_in[14];

    float* ws = (float*)d_ws;
    float* ta_w   = ws;                                    // 256
    float* pb_w   = ws + 256;                              // 256
    float* biases = ws + 512;                              // 4
    float* params = ws + 516;                              // 16
    float* a_arr  = ws + 532;                              // 25088
    float* bsc      = a_arr + BATCH * NPIX;                // 25088
    float* s_sorted = bsc + BATCH * NPIX;                  // 25088
    int*   idx_sorted = (int*)(s_sorted + BATCH * NPIX);   // 25088
    int*   bstart   = idx_sorted + BATCH * NPIX;           // 8*4097
    float* CS1    = (float*)(bstart + BATCH * (NB + 1));   // 102400
    float* CS2    = CS1 + BATCH * 100 * CI;                // 102400
    unsigned short* Bfrag_g = (unsigned short*)(CS2 + BATCH * 100 * CI); // 32768
    unsigned short* Bfrag_w = Bfrag_g + 32768;             // 32768
    unsigned short* gxg = Bfrag_w + 32768;                 // 8*3136*128 bf16

    k_fold<<<17, 256, 0, stream>>>(wf_w, theta_w, theta_b, phi_w, phi_b,
                                   g_w, wz_w, ta_w, pb_w, biases,
                                   Bfrag_g, Bfrag_w);

    k_gemm<<<dim3(NCHUNK, BATCH), 256, 0, stream>>>(
        x, Bfrag_g, g_b, ta_w, pb_w, biases, gxg, a_arr, bsc);

    k_bucketsort<<<BATCH, 1024, 0, stream>>>(bsc, s_sorted, idx_sorted,
                                             bstart, params);

    k_csum<<<dim3(NCHUNK, BATCH), 128, 0, stream>>>(
        gxg, s_sorted, idx_sorted, CS1, CS2);

    k_suffix<<<dim3(BATCH, 2), 1024, 0, stream>>>(CS1, CS2);

    k_final<<<dim3(NCHUNK, BATCH), 256, 0, stream>>>(
        x, a_arr, wf_b, CS1, CS2, bstart, params, Bfrag_w,
        wz_b, bn_g, bn_b, bn_m, bn_v, (float*)d_out);
}

// Round 2
// 151.517 us; speedup vs baseline: 1.0621x; 1.0162x over previous
//
#include <hip/hip_runtime.h>
#include <cfloat>
#include <math.h>

#define BATCH 8
#define CH 256
#define CI 128
#define NPIX 3136   // 56*56
#define NCHUNK 98   // 3136/32
#define NB 4096     // buckets for the scatter sort
#define BN_EPS 1e-5f

typedef __attribute__((ext_vector_type(8))) short bf16x8;   // 8 bf16 in 4 VGPRs
typedef __attribute__((ext_vector_type(4))) float f32x4;

__device__ __forceinline__ float bf2f(unsigned short u) {
    union { unsigned int i; float f; } x; x.i = ((unsigned int)u) << 16; return x.f;
}
__device__ __forceinline__ unsigned short f2bf(float f) {
    union { float f; unsigned int i; } x; x.f = f;
    unsigned int u = x.i;
    return (unsigned short)((u + 0x7FFFu + ((u >> 16) & 1u)) >> 16);  // RNE
}

// ---------------------------------------------------------------------------
// K1: block 0: fold wf into theta/phi weights (+biases).
// blocks 1-8:  swizzle g_w^T into bf16 B-fragments  (K=256, N=128)
// blocks 9-16: swizzle wz_w^T into bf16 B-fragments (K=128, N=256)
// B-frag layout per MFMA 16x16x32: lane l, j: B[k=(l>>4)*8+j][n=l&15]
// ---------------------------------------------------------------------------
__global__ __launch_bounds__(256) void k_fold(
    const float* __restrict__ wf_w,
    const float* __restrict__ theta_w, const float* __restrict__ theta_b,
    const float* __restrict__ phi_w,   const float* __restrict__ phi_b,
    const float* __restrict__ g_w,     const float* __restrict__ wz_w,
    float* __restrict__ ta_w, float* __restrict__ pb_w, float* __restrict__ biases,
    unsigned short* __restrict__ Bfrag_g, unsigned short* __restrict__ Bfrag_w)
{
    const int bk = blockIdx.x, tid = threadIdx.x;
    if (bk == 0) {
        float ta = 0.f, pb = 0.f;
        for (int c = 0; c < CI; ++c) {
            ta += wf_w[c]      * theta_w[c * CH + tid];
            pb += wf_w[CI + c] * phi_w[c * CH + tid];
        }
        ta_w[tid] = ta;
        pb_w[tid] = pb;
        if (tid == 0) {
            float tb = 0.f, pbb = 0.f;
            for (int c = 0; c < CI; ++c) {
                tb  += wf_w[c]      * theta_b[c];
                pbb += wf_w[CI + c] * phi_b[c];
            }
            biases[0] = tb;
            biases[1] = pbb;
        }
    } else if (bk <= 8) {
        const int base_pair = (bk - 1) * 8;
        for (int e = tid; e < 4096; e += 256) {
            int pp = e >> 9, lane = (e >> 3) & 63, j = e & 7;
            int pair = base_pair + pp;
            int ks = pair >> 3, nt = pair & 7;
            int k = ks * 32 + (lane >> 4) * 8 + j;
            int n = nt * 16 + (lane & 15);
            Bfrag_g[(size_t)pair * 512 + lane * 8 + j] = f2bf(g_w[n * CH + k]);
        }
    } else {
        const int base_pair = (bk - 9) * 8;
        for (int e = tid; e < 4096; e += 256) {
            int pp = e >> 9, lane = (e >> 3) & 63, j = e & 7;
            int pair = base_pair + pp;
            int ks = pair >> 4, nt = pair & 15;
            int k = ks * 32 + (lane >> 4) * 8 + j;
            int n = nt * 16 + (lane & 15);
            Bfrag_w[(size_t)pair * 512 + lane * 8 + j] = f2bf(wz_w[n * CI + k]);
        }
    }
}

// ---------------------------------------------------------------------------
// K2 (fused conv+gemm), 64-pixel tiles: two 32-px staging halves share the
// fp32 xs tile; fused {a/bsc dots + bf16 transpose}; MFMA M=64 reuses each
// B-fragment pair across 4 M-tiles (half the Bfrag_g traffic of 32-px tiles).
// grid (49, B), block 256. 392 blocks @ 2/CU -> one residency round.
// gout aliases the dead xs tile.
// ---------------------------------------------------------------------------
__global__ __launch_bounds__(256) void k_gemm(
    const float* __restrict__ x,
    const unsigned short* __restrict__ Bfrag_g,
    const float* __restrict__ g_b,
    const float* __restrict__ ta_w, const float* __restrict__ pb_w,
    const float* __restrict__ biases,
    unsigned short* __restrict__ gxg,
    float* __restrict__ a_out, float* __restrict__ bsc_out)
{
    __shared__ float xs[CH][36];              // 36.9 KB, reused per half
    __shared__ unsigned short xsb[64 * 264];  // 33.8 KB bf16 transposed tile
    __shared__ float ra[8][32], rp[8][32];    // 2 KB
    unsigned short* gout = (unsigned short*)&xs[0][0];  // alias (need 17.4 KB)

    const int b  = blockIdx.y;
    const int n0 = blockIdx.x * 64;
    const int tid = threadIdx.x;
    const int p = tid & 31;        // pixel within half
    const int g = tid >> 5;        // channel group of 32

    for (int half = 0; half < 2; ++half) {
        for (int t = tid; t < CH * 8; t += 256) {
            int c = t >> 3, n4 = t & 7;
            const float4* src = (const float4*)(x + ((size_t)b * CH + c) * NPIX + n0 + half * 32);
            *((float4*)&xs[c][n4 * 4]) = src[n4];
        }
        __syncthreads();

        // fused: a/bsc partial dots (fp32) + bf16 transpose, one pass over xs
        {
            const int cbase = g * 32;
            float aa = 0.f, pp = 0.f;
            unsigned int* dst = (unsigned int*)&xsb[(half * 32 + p) * 264 + cbase];
#pragma unroll
            for (int q = 0; q < 16; ++q) {
                int c0 = cbase + 2 * q;
                float lo = xs[c0][p];
                float hi = xs[c0 + 1][p];
                aa += ta_w[c0] * lo + ta_w[c0 + 1] * hi;
                pp += pb_w[c0] * lo + pb_w[c0 + 1] * hi;
                dst[q] = (unsigned int)f2bf(lo) | ((unsigned int)f2bf(hi) << 16);
            }
            ra[g][p] = aa; rp[g][p] = pp;
        }
        __syncthreads();

        // reduce runs between barriers; next half's xs load may overlap (xs
        // reads done pre-barrier; ra/rp re-written only after next barrier)
        if (tid < 32) {
            float sa = 0.f, sp = 0.f;
#pragma unroll
            for (int gg = 0; gg < 8; ++gg) { sa += ra[gg][tid]; sp += rp[gg][tid]; }
            a_out[b * NPIX + n0 + half * 32 + tid]   = sa + biases[0];
            bsc_out[b * NPIX + n0 + half * 32 + tid] = sp + biases[1];
        }
    }

    // MFMA: D[px(64) x o(128)] = xsb(64x256) * g_wT(256x128)
    const int w = tid >> 6, l = tid & 63, lm = l & 15, lq = l >> 4;
    f32x4 acc[4][2];
#pragma unroll
    for (int mi = 0; mi < 4; ++mi)
#pragma unroll
        for (int ni = 0; ni < 2; ++ni) acc[mi][ni] = (f32x4){0.f, 0.f, 0.f, 0.f};

#pragma unroll
    for (int ks = 0; ks < 8; ++ks) {
        bf16x8 b0 = *(const bf16x8*)(Bfrag_g + ((size_t)(ks * 8 + w * 2) * 64 + l) * 8);
        bf16x8 b1 = *(const bf16x8*)(Bfrag_g + ((size_t)(ks * 8 + w * 2 + 1) * 64 + l) * 8);
#pragma unroll
        for (int mi = 0; mi < 4; ++mi) {
            bf16x8 a0 = *(const bf16x8*)&xsb[(mi * 16 + lm) * 264 + ks * 32 + lq * 8];
            acc[mi][0] = __builtin_amdgcn_mfma_f32_16x16x32_bf16(a0, b0, acc[mi][0], 0, 0, 0);
            acc[mi][1] = __builtin_amdgcn_mfma_f32_16x16x32_bf16(a0, b1, acc[mi][1], 0, 0, 0);
        }
    }

    // xs fully read before the last barrier -> gout (alias) safe to write
#pragma unroll
    for (int mi = 0; mi < 4; ++mi)
#pragma unroll
        for (int ni = 0; ni < 2; ++ni) {
            int o = w * 32 + ni * 16 + lm;
            float gb = g_b[o];
#pragma unroll
            for (int r = 0; r < 4; ++r) {
                int m = mi * 16 + lq * 4 + r;
                gout[m * 136 + o] = f2bf(acc[mi][ni][r] + gb);
            }
        }
    __syncthreads();

    {
        const int n = tid >> 2, ch = tid & 3;   // 64 rows x 4 groups of 32 ch
        const uint4* s = (const uint4*)&gout[n * 136 + ch * 32];
        uint4* d = (uint4*)(gxg + ((size_t)(b * NPIX + n0 + n)) * CI + ch * 32);
        d[0] = s[0]; d[1] = s[1]; d[2] = s[2]; d[3] = s[3];
    }
}

// ---------------------------------------------------------------------------
// K3: per-batch bucket scatter, wave-parallel. grid (B), block 1024.
// ---------------------------------------------------------------------------
__global__ __launch_bounds__(1024) void k_bucketsort(
    const float* __restrict__ bsc,
    float* __restrict__ s_sorted, int* __restrict__ idx_sorted,
    int* __restrict__ bstart, float* __restrict__ params)
{
    __shared__ int hist[NB];
    __shared__ int cnt[NB];
    __shared__ float wmin[16], wmax[16];
    __shared__ int wtot[16], woff[16];
    __shared__ float sh_min, sh_scale;

    const int b = blockIdx.x, tid = threadIdx.x;
    const int lane = tid & 63, wid = tid >> 6;

#pragma unroll
    for (int k = 0; k < 4; ++k) { hist[tid + k * 1024] = 0; cnt[tid + k * 1024] = 0; }

    float v[4];
    float lmin = FLT_MAX, lmax = -FLT_MAX;
#pragma unroll
    for (int k = 0; k < 4; ++k) {
        int i = tid + k * 1024;
        if (i < NPIX) {
            float t = bsc[b * NPIX + i];
            v[k] = t;
            lmin = fminf(lmin, t);
            lmax = fmaxf(lmax, t);
        }
    }
#pragma unroll
    for (int m = 32; m >= 1; m >>= 1) {
        lmin = fminf(lmin, __shfl_xor(lmin, m));
        lmax = fmaxf(lmax, __shfl_xor(lmax, m));
    }
    if (lane == 0) { wmin[wid] = lmin; wmax[wid] = lmax; }
    __syncthreads();

    if (tid < 16) {
        float a = wmin[tid], c = wmax[tid];
#pragma unroll
        for (int m = 8; m >= 1; m >>= 1) {
            a = fminf(a, __shfl_xor(a, m));
            c = fmaxf(c, __shfl_xor(c, m));
        }
        if (tid == 0) {
            float range = c - a;
            float scale = (range > 0.f) ? (float)NB / range : 0.f;
            sh_min = a; sh_scale = scale;
            params[b * 2] = a; params[b * 2 + 1] = scale;
        }
    }
    __syncthreads();

    const float bmin = sh_min, scale = sh_scale;
    int q[4];
#pragma unroll
    for (int k = 0; k < 4; ++k) {
        int i = tid + k * 1024;
        if (i < NPIX) {
            int qq = (int)((v[k] - bmin) * scale);
            qq = (qq < 0) ? 0 : ((qq > NB - 1) ? NB - 1 : qq);
            q[k] = qq;
            atomicAdd(&hist[qq], 1);
        }
    }
    __syncthreads();

    const int base4 = tid * 4;
    int h0 = hist[base4], h1 = hist[base4 + 1], h2 = hist[base4 + 2], h3 = hist[base4 + 3];
    int s = h0 + h1 + h2 + h3;
    int incl = s;
#pragma unroll
    for (int off = 1; off < 64; off <<= 1) {
        int t = __shfl_up(incl, off);
        if (lane >= off) incl += t;
    }
    if (lane == 63) wtot[wid] = incl;
    __syncthreads();
    if (tid < 16) {
        int t = wtot[tid];
        int wi = t;
#pragma unroll
        for (int off = 1; off < 16; off <<= 1) {
            int u = __shfl_up(wi, off);
            if (tid >= off) wi += u;
        }
        woff[tid] = wi - t;
    }
    __syncthreads();
    int excl = woff[wid] + (incl - s);
    hist[base4]     = excl;
    hist[base4 + 1] = excl + h0;
    hist[base4 + 2] = excl + h0 + h1;
    hist[base4 + 3] = excl + h0 + h1 + h2;
    __syncthreads();

#pragma unroll
    for (int k = 0; k < 4; ++k) {
        int i = tid + k * 1024;
        bstart[b * (NB + 1) + i] = hist[i];
    }
    if (tid == 0) bstart[b * (NB + 1) + NB] = NPIX;

#pragma unroll
    for (int k = 0; k < 4; ++k) {
        int i = tid + k * 1024;
        if (i < NPIX) {
            int pos = hist[q[k]] + atomicAdd(&cnt[q[k]], 1);
            s_sorted[b * NPIX + pos]   = v[k];
            idx_sorted[b * NPIX + pos] = i;
        }
    }
}

// ---------------------------------------------------------------------------
// K4: per-chunk sums, 1-wave blocks. Sorted (idx,val) pairs held in lanes
// 0-31 and broadcast via __shfl (no LDS, no barrier); gathered gxg rows read
// as full 256 B dword lines (2 channels/lane); float2 stores.
// grid (NCHUNK, B), block 64.
// ---------------------------------------------------------------------------
__global__ __launch_bounds__(64) void k_csum(
    const unsigned short* __restrict__ gxg,
    const float* __restrict__ s_sorted, const int* __restrict__ idx_sorted,
    float* __restrict__ CS1, float* __restrict__ CS2)
{
    const int b = blockIdx.y, c = blockIdx.x, t = threadIdx.x;
    const int base = b * NPIX + c * 32;

    int   my_i = idx_sorted[base + (t & 31)];
    float my_v = s_sorted[base + (t & 31)];

    float a1x = 0.f, a1y = 0.f, a2x = 0.f, a2y = 0.f;
#pragma unroll 8
    for (int rr = 0; rr < 32; ++rr) {
        int   row = __shfl(my_i, rr);
        float sv  = __shfl(my_v, rr);
        unsigned int u = *(const unsigned int*)(gxg + ((size_t)(b * NPIX + row)) * CI + 2 * t);
        float v0 = bf2f((unsigned short)(u & 0xffffu));
        float v1 = bf2f((unsigned short)(u >> 16));
        a1x += v0;      a1y += v1;
        a2x += sv * v0; a2y += sv * v1;
    }
    float2* p1 = (float2*)&CS1[(b * 100 + c) * CI];
    float2* p2 = (float2*)&CS2[(b * 100 + c) * CI];
    p1[t] = make_float2(a1x, a1y);
    p2[t] = make_float2(a2x, a2y);
}

// ---------------------------------------------------------------------------
// K5: suffix scan over 98 chunks, two-level parallel. grid (B, 2), blk 1024.
// ---------------------------------------------------------------------------
__global__ __launch_bounds__(1024) void k_suffix(
    float* __restrict__ CS1, float* __restrict__ CS2)
{
    __shared__ float buf[NCHUNK * CI];   // 49 KB
    __shared__ float tot[8][CI];         // 4 KB
    const int b = blockIdx.x, tid = threadIdx.x;
    float* __restrict__ CS = blockIdx.y ? CS2 : CS1;

    for (int i = tid; i < NCHUNK * CI; i += 1024) buf[i] = CS[b * 100 * CI + i];
    __syncthreads();

    const int seg = tid >> 7, o = tid & 127;
    const int c0 = seg * 13;
    const int c1 = (seg == 7) ? NCHUNK : c0 + 13;   // 13*7 + 7 = 98
    {
        float acc = 0.f;
        for (int c = c1 - 1; c >= c0; --c) {
            acc += buf[c * CI + o];
            buf[c * CI + o] = acc;
        }
        tot[seg][o] = acc;
    }
    __syncthreads();
    {
        float off = 0.f;
#pragma unroll
        for (int s2 = 7; s2 >= 1; --s2) if (s2 > seg) off += tot[s2][o];
        if (off != 0.f || seg < 7) {
            for (int c = c0; c < c1; ++c) buf[c * CI + o] += off;
        }
    }
    __syncthreads();
    for (int i = tid; i < NCHUNK * CI; i += 1024) CS[b * 100 * CI + i] = buf[i];
    if (tid < CI) {
        CS[(b * 100 + 98) * CI + tid] = 0.f;
        CS[(b * 100 + 99) * CI + tid] = 0.f;
    }
}

// ---------------------------------------------------------------------------
// K6 (fused), 64-pixel tiles: bucket lookup -> y rows from L2-resident CS
// tables -> MFMA wz-GEMM (M=64, B-fragments reused across 4 M-tiles) ->
// direct BN+residual float4 epilogue from C-fragments. grid (49, B), blk 256.
// ---------------------------------------------------------------------------
__global__ __launch_bounds__(256) void k_final(
    const float* __restrict__ x,
    const float* __restrict__ a_arr, const float* __restrict__ wf_b,
    const float* __restrict__ CS1, const float* __restrict__ CS2,
    const int* __restrict__ bstart, const float* __restrict__ params,
    const unsigned short* __restrict__ Bfrag_w,
    const float* __restrict__ wz_b,
    const float* __restrict__ bn_g, const float* __restrict__ bn_b,
    const float* __restrict__ bn_m, const float* __restrict__ bn_v,
    float* __restrict__ out)
{
    __shared__ unsigned short ys[64 * 136];  // 17.4 KB bf16 y tile
    __shared__ int   rs[64];
    __shared__ float ts[64];

    const int b = blockIdx.y;
    const int n0 = blockIdx.x * 64;
    const int tid = threadIdx.x;

    if (tid < 64) {
        float t = a_arr[b * NPIX + n0 + tid] + wf_b[0];
        float bmin = params[b * 2], scale = params[b * 2 + 1];
        float fq = (-t - bmin) * scale;
        int kb = (int)(fq + 0.5f);
        kb = (kb < 0) ? 0 : ((kb > NB) ? NB : kb);
        int r = bstart[b * (NB + 1) + kb];
        int cstar = (r + 16) >> 5;           // nearest chunk boundary, 0..98
        cstar = (cstar > 98) ? 98 : cstar;
        rs[tid] = cstar;
        ts[tid] = t;
    }
    __syncthreads();

    const int o = tid & 127;
    const int h = tid >> 7;
    const float invN = 1.0f / (float)NPIX;

#pragma unroll 4
    for (int i = 0; i < 32; ++i) {
        int n = h * 32 + i;
        int cb = (b * 100 + rs[n]) * CI + o;
        float S1 = CS1[cb], S2 = CS2[cb];
        ys[n * 136 + o] = f2bf((ts[n] * S1 + S2) * invN);
    }
    __syncthreads();

    const int w = tid >> 6, l = tid & 63, lm = l & 15, lq = l >> 4;

    float invv[4], biasv[4];
#pragma unroll
    for (int ni = 0; ni < 4; ++ni) {
        int cc = w * 64 + ni * 16 + lm;
        float iv = bn_g[cc] * rsqrtf(bn_v[cc] + BN_EPS);
        invv[ni] = iv;
        biasv[ni] = (wz_b[cc] - bn_m[cc]) * iv + bn_b[cc];
    }

    // MFMA: D[px(64) x cc(256)] = ys(64x128) * wz_wT(128x256)
    f32x4 acc[4][4];
#pragma unroll
    for (int mi = 0; mi < 4; ++mi)
#pragma unroll
        for (int ni = 0; ni < 4; ++ni) acc[mi][ni] = (f32x4){0.f, 0.f, 0.f, 0.f};

#pragma unroll
    for (int ks = 0; ks < 4; ++ks) {
        bf16x8 af[4];
#pragma unroll
        for (int mi = 0; mi < 4; ++mi)
            af[mi] = *(const bf16x8*)&ys[(mi * 16 + lm) * 136 + ks * 32 + lq * 8];
#pragma unroll
        for (int ni = 0; ni < 4; ++ni) {
            bf16x8 bb = *(const bf16x8*)(Bfrag_w + ((size_t)(ks * 16 + w * 4 + ni) * 64 + l) * 8);
#pragma unroll
            for (int mi = 0; mi < 4; ++mi)
                acc[mi][ni] = __builtin_amdgcn_mfma_f32_16x16x32_bf16(af[mi], bb, acc[mi][ni], 0, 0, 0);
        }
    }

    // direct epilogue: lane fragment = 4 consecutive pixels of one channel
#pragma unroll
    for (int mi = 0; mi < 4; ++mi)
#pragma unroll
        for (int ni = 0; ni < 4; ++ni) {
            int cc = w * 64 + ni * 16 + lm;
            int m  = mi * 16 + lq * 4;
            size_t base = ((size_t)b * CH + cc) * NPIX + n0 + m;
            const float4 xv = *(const float4*)(x + base);
            float4 ov;
            ov.x = acc[mi][ni][0] * invv[ni] + biasv[ni] + xv.x;
            ov.y = acc[mi][ni][1] * invv[ni] + biasv[ni] + xv.y;
            ov.z = acc[mi][ni][2] * invv[ni] + biasv[ni] + xv.z;
            ov.w = acc[mi][ni][3] * invv[ni] + biasv[ni] + xv.w;
            *(float4*)(out + base) = ov;
        }
}

// ---------------------------------------------------------------------------
extern "C" void kernel_launch(void* const* d_in, const int* in_sizes, int n_in,
                              void* d_out, int out_size, void* d_ws, size_t ws_size,
                              hipStream_t stream)
{
    const float* x       = (const float*)d_in[0];
    const float* g_w     = (const float*)d_in[1];
    const float* g_b     = (const float*)d_in[2];
    const float* theta_w = (const float*)d_in[3];
    const float* theta_b = (const float*)d_in[4];
    const float* phi_w   = (const float*)d_in[5];
    const float* phi_b   = (const float*)d_in[6];
    const float* wf_w    = (const float*)d_in[7];
    const float* wf_b    = (const float*)d_in[8];
    const float* wz_w    = (const float*)d_in[9];
    const float* wz_b    = (const float*)d_in[10];
    const float* bn_g    = (const float*)d_in[11];
    const float* bn_b    = (const float*)d_in[12];
    const float* bn_m    = (const float*)d_in[13];
    const float* bn_v    = (const float*)d_in[14];

    float* ws = (float*)d_ws;
    float* ta_w   = ws;                                    // 256
    float* pb_w   = ws + 256;                              // 256
    float* biases = ws + 512;                              // 4
    float* params = ws + 516;                              // 16
    float* a_arr  = ws + 532;                              // 25088
    float* bsc      = a_arr + BATCH * NPIX;                // 25088
    float* s_sorted = bsc + BATCH * NPIX;                  // 25088
    int*   idx_sorted = (int*)(s_sorted + BATCH * NPIX);   // 25088
    int*   bstart   = idx_sorted + BATCH * NPIX;           // 8*4097
    float* CS1    = (float*)(bstart + BATCH * (NB + 1));   // 102400
    float* CS2    = CS1 + BATCH * 100 * CI;                // 102400
    unsigned short* Bfrag_g = (unsigned short*)(CS2 + BATCH * 100 * CI); // 32768
    unsigned short* Bfrag_w = Bfrag_g + 32768;             // 32768
    unsigned short* gxg = Bfrag_w + 32768;                 // 8*3136*128 bf16

    k_fold<<<17, 256, 0, stream>>>(wf_w, theta_w, theta_b, phi_w, phi_b,
                                   g_w, wz_w, ta_w, pb_w, biases,
                                   Bfrag_g, Bfrag_w);

    k_gemm<<<dim3(49, BATCH), 256, 0, stream>>>(
        x, Bfrag_g, g_b, ta_w, pb_w, biases, gxg, a_arr, bsc);

    k_bucketsort<<<BATCH, 1024, 0, stream>>>(bsc, s_sorted, idx_sorted,
                                             bstart, params);

    k_csum<<<dim3(NCHUNK, BATCH), 64, 0, stream>>>(
        gxg, s_sorted, idx_sorted, CS1, CS2);

    k_suffix<<<dim3(BATCH, 2), 1024, 0, stream>>>(CS1, CS2);

    k_final<<<dim3(49, BATCH), 256, 0, stream>>>(
        x, a_arr, wf_b, CS1, CS2, bstart, params, Bfrag_w,
        wz_b, bn_g, bn_b, bn_m, bn_v, (float*)d_out);
}